// Round 10
// baseline (580.813 us; speedup 1.0000x reference)
//
#include <hip/hip_runtime.h>
#include <hip/hip_bf16.h>
#include <cstdint>

#define NEG_SLOPE 0.2f

typedef __attribute__((ext_vector_type(8))) short bf16x8;
typedef __attribute__((ext_vector_type(4))) float f32x4;

__device__ __forceinline__ float bf2f(uint32_t u) {
  union { float f; uint32_t i; } v;
  v.i = u << 16;
  return v.f;
}
__device__ __forceinline__ float lo16(uint32_t u) {
  union { float f; uint32_t i; } v;
  v.i = u << 16;
  return v.f;
}
__device__ __forceinline__ float hi16(uint32_t u) {
  union { float f; uint32_t i; } v;
  v.i = u & 0xffff0000u;
  return v.f;
}
__device__ __forceinline__ ushort f2bf(float f) {
  union { float f; uint32_t i; } v;
  v.f = f;
  uint32_t r = v.i + 0x7FFF + ((v.i >> 16) & 1);  // round-nearest-even
  return (ushort)(r >> 16);
}

// ---------------------------------------------------------------------------
// prep: cast x -> bf16, transpose+cast W1/W2/W3, CSR count pass, zero sums.
// ---------------------------------------------------------------------------
__global__ void prep_kernel(const float4* __restrict__ x,
                            uint2* __restrict__ x_bf, int n_x4,
                            const float* __restrict__ W1,
                            ushort* __restrict__ W1T,
                            const float* __restrict__ W2,
                            ushort* __restrict__ W2T,
                            const float* __restrict__ W3,
                            ushort* __restrict__ W3T,
                            const int* __restrict__ dst, int* __restrict__ cnt,
                            float* __restrict__ sums, int E) {
  int i = blockIdx.x * 256 + threadIdx.x;
  const int r0 = n_x4;
  const int r1 = r0 + 512 * 128;
  const int r2 = r1 + 64 * 512;
  const int r3 = r2 + 64 * 64;
  const int r4 = r3 + E;
  const int r5 = r4 + 64 * 64;
  if (i < r0) {
    float4 v = x[i];
    uint2 o;
    o.x = (uint32_t)f2bf(v.x) | ((uint32_t)f2bf(v.y) << 16);
    o.y = (uint32_t)f2bf(v.z) | ((uint32_t)f2bf(v.w) << 16);
    x_bf[i] = o;
  } else if (i < r1) {
    int idx = i - r0;
    int n = idx >> 7, k = idx & 127;
    W1T[idx] = f2bf(W1[(size_t)k * 512 + n]);
  } else if (i < r2) {
    int idx = i - r1;
    int n = idx >> 9, k = idx & 511;
    W2T[idx] = f2bf(W2[(size_t)k * 64 + n]);
  } else if (i < r3) {
    int idx = i - r2;
    int n = idx >> 6, k = idx & 63;
    W3T[idx] = f2bf(W3[(size_t)k * 64 + n]);
  } else if (i < r4) {
    atomicAdd(&cnt[dst[i - r3]], 1);
  } else if (i < r5) {
    sums[i - r4] = 0.f;
  }
}

// ---------------------------------------------------------------------------
// Fused dispatch: GEMM1 logits-only (al_s1/al_d1 from MFMA accumulators,
// h1 NOT stored) for blocks [0, gemmBlocks); block-scan tail.
// ---------------------------------------------------------------------------
__global__ __launch_bounds__(256) void gemm1_scan_kernel(
    const ushort* __restrict__ A, const ushort* __restrict__ BT,
    const float* __restrict__ a1s, const float* __restrict__ a1d,
    float* __restrict__ al_s, float* __restrict__ al_d, int M, int gemmBlocks,
    const int* __restrict__ scan_in, int* __restrict__ scan_out,
    int* __restrict__ bsum, int n) {
  if (blockIdx.x >= gemmBlocks) {
    __shared__ int sm[256];
    const int sb = blockIdx.x - gemmBlocks;
    int gid = sb * 256 + threadIdx.x;
    int v = (gid < n) ? scan_in[gid] : 0;
    sm[threadIdx.x] = v;
    __syncthreads();
    for (int off = 1; off < 256; off <<= 1) {
      int t = (threadIdx.x >= off) ? sm[threadIdx.x - off] : 0;
      __syncthreads();
      sm[threadIdx.x] += t;
      __syncthreads();
    }
    if (gid < n) scan_out[gid] = sm[threadIdx.x];
    if (threadIdx.x == 255) bsum[sb] = sm[255];
    return;
  }
  const int K = 128;
  const int wave = threadIdx.x >> 6;
  const int lane = threadIdx.x & 63;
  const int bx = blockIdx.x & 3;
  const int by = blockIdx.x >> 2;
  const int rt = by * 4 + wave;
  const int r0 = rt * 16;
  if (r0 >= M) return;
  const int n0 = bx * 128;
  const int l15 = lane & 15, q = lane >> 4;
  const ushort* Ap = A + (size_t)(r0 + l15) * K + q * 8;
  f32x4 acc[8] = {};
  for (int k0 = 0; k0 < K; k0 += 32) {
    bf16x8 a = *(const bf16x8*)(Ap + k0);
#pragma unroll
    for (int j = 0; j < 8; ++j) {
      const bf16x8 b =
          *(const bf16x8*)(BT + (size_t)(n0 + j * 16 + l15) * K + q * 8 + k0);
      acc[j] = __builtin_amdgcn_mfma_f32_16x16x32_bf16(a, b, acc[j], 0, 0, 0);
    }
  }
  float als_p[2][4] = {{0.f}};
  float ald_p[2][4] = {{0.f}};
#pragma unroll
  for (int j = 0; j < 8; ++j) {
    int head = bx * 2 + (j >> 2);
    int cih = (j & 3) * 16 + l15;
    float wsc = a1s[head * 64 + cih];
    float wdc = a1d[head * 64 + cih];
#pragma unroll
    for (int r = 0; r < 4; ++r) {
      als_p[j >> 2][r] = fmaf(acc[j][r], wsc, als_p[j >> 2][r]);
      ald_p[j >> 2][r] = fmaf(acc[j][r], wdc, ald_p[j >> 2][r]);
    }
  }
#pragma unroll
  for (int g = 0; g < 2; ++g)
#pragma unroll
    for (int r = 0; r < 4; ++r) {
      float vs = als_p[g][r], vd = ald_p[g][r];
#pragma unroll
      for (int off = 1; off < 16; off <<= 1) {
        vs += __shfl_xor(vs, off);
        vd += __shfl_xor(vd, off);
      }
      if (l15 == 0) {
        int row = r0 + q * 4 + r;
        al_s[(size_t)row * 8 + bx * 2 + g] = vs;
        al_d[(size_t)row * 8 + bx * 2 + g] = vd;
      }
    }
}

// ---------------------------------------------------------------------------
// GEMM (N=64) + fused al (H=1): C[M,64] = A[M,K] @ BT[64,K].
// ---------------------------------------------------------------------------
__global__ __launch_bounds__(256) void gemm_n64_al(
    const ushort* __restrict__ A, const ushort* __restrict__ BT,
    ushort* __restrict__ C, const float* __restrict__ asrc,
    const float* __restrict__ adst, float* __restrict__ al_s,
    float* __restrict__ al_d, int M, int K) {
  const int wave = threadIdx.x >> 6;
  const int lane = threadIdx.x & 63;
  const int rt = blockIdx.y * 4 + wave;
  const int r0 = rt * 16;
  if (r0 >= M) return;
  const int l15 = lane & 15, q = lane >> 4;
  const ushort* Ap = A + (size_t)(r0 + l15) * K + q * 8;
  f32x4 acc[4] = {};
  for (int k0 = 0; k0 < K; k0 += 32) {
    bf16x8 a = *(const bf16x8*)(Ap + k0);
#pragma unroll
    for (int j = 0; j < 4; ++j) {
      const bf16x8 b =
          *(const bf16x8*)(BT + (size_t)(j * 16 + l15) * K + q * 8 + k0);
      acc[j] = __builtin_amdgcn_mfma_f32_16x16x32_bf16(a, b, acc[j], 0, 0, 0);
    }
  }
#pragma unroll
  for (int j = 0; j < 4; ++j)
#pragma unroll
    for (int r = 0; r < 4; ++r) {
      int row = r0 + q * 4 + r;
      C[(size_t)row * 64 + j * 16 + l15] = f2bf(acc[j][r]);
    }
  float als_p[4] = {0.f, 0.f, 0.f, 0.f};
  float ald_p[4] = {0.f, 0.f, 0.f, 0.f};
#pragma unroll
  for (int j = 0; j < 4; ++j) {
    float wsc = asrc[j * 16 + l15];
    float wdc = adst[j * 16 + l15];
#pragma unroll
    for (int r = 0; r < 4; ++r) {
      als_p[r] = fmaf(acc[j][r], wsc, als_p[r]);
      ald_p[r] = fmaf(acc[j][r], wdc, ald_p[r]);
    }
  }
#pragma unroll
  for (int r = 0; r < 4; ++r) {
    float vs = als_p[r], vd = ald_p[r];
#pragma unroll
    for (int off = 1; off < 16; off <<= 1) {
      vs += __shfl_xor(vs, off);
      vd += __shfl_xor(vd, off);
    }
    if (l15 == 0) {
      int row = r0 + q * 4 + r;
      al_s[row] = vs;
      al_d[row] = vd;
    }
  }
}

__global__ void scan_final2(const int* __restrict__ inc,
                            const int* __restrict__ bsum,
                            int* __restrict__ indptr, int* __restrict__ fill,
                            int n) {
  __shared__ int sm[256];
  const int t = threadIdx.x, bx = blockIdx.x;
  sm[t] = (t < bx) ? bsum[t] : 0;  // gridDim <= 256
  __syncthreads();
  for (int off = 128; off; off >>= 1) {
    if (t < off) sm[t] += sm[t + off];
    __syncthreads();
  }
  const int prefix = sm[0];
  int gid = bx * 256 + t;
  if (gid < n) {
    int val = inc[gid] + prefix;
    indptr[gid + 1] = val;
    fill[gid + 1] = val;
  }
  if (gid == 0) {
    indptr[0] = 0;
    fill[0] = 0;
  }
}

__global__ void scatter_kernel(const int* __restrict__ src,
                               const int* __restrict__ dst,
                               int* __restrict__ fill,
                               int* __restrict__ csr_src, int E) {
  int e = blockIdx.x * 256 + threadIdx.x;
  if (e < E) {
    int pos = atomicAdd(&fill[dst[e]], 1);
    csr_src[pos] = src[e];
  }
}

// ---------------------------------------------------------------------------
// Layer-1 aggregation in x-space (alpha commutes with W1):
// agg[d,h,:] = (1/den_h) * sum_e alpha_e^h * x[src_e,:]   (128 dims, bf16 out)
// One wave per dst node. Lane l holds x-dword l (dims 2l,2l+1) for all 8
// heads (16 acc regs). Gather is a 256 B x-row (4B/lane) -- 4x smaller table
// and 4x less demand than gathering h1 rows.
// ---------------------------------------------------------------------------
__global__ __launch_bounds__(256) void attn1_agg_kernel(
    const int* __restrict__ indptr, const int* __restrict__ csr_src,
    const float* __restrict__ al_s, const float* __restrict__ al_d,
    const uint32_t* __restrict__ x_bf, ushort* __restrict__ agg, int Nn) {
  const int w = (blockIdx.x * 256 + threadIdx.x) >> 6;
  const int l = threadIdx.x & 63;
  if (w >= Nn) return;
  const int d = w;
  const int start = indptr[d];
  const int deg = indptr[d + 1] - start;
  const int total = deg + 1;  // + self loop
  const int slot = l >> 3;    // alpha-stage edge slot
  const int hh = l & 7;       // alpha-stage head
  const float ald_c = al_d[(size_t)d * 8 + hh];

  float acc[8][2] = {};
  float den = 0.f;

  // prologue: prefetch group 0 logits
  int s_p = d;
  float a_p = 0.f;
  if (slot < total) {
    s_p = (slot < deg) ? csr_src[start + slot] : d;
    a_p = al_s[(size_t)s_p * 8 + hh];
  }

  for (int e0 = 0; e0 < total; e0 += 8) {
    const int el = e0 + slot;
    const int s_j = s_p;
    float v = a_p + ald_c;
    v = fmaxf(v, NEG_SLOPE * v);
    const float u = (el < total) ? __expf(v) : 0.f;
    den += u;
    const int eln = el + 8;
    if (eln < total) {
      s_p = (eln < deg) ? csr_src[start + eln] : d;
      a_p = al_s[(size_t)s_p * 8 + hh];
    } else {
      s_p = d;
      a_p = 0.f;
    }
#pragma unroll
    for (int e = 0; e < 8; ++e) {
      const int s = __shfl(s_j, e * 8);
      const uint32_t xv = x_bf[(size_t)s * 64 + l];
      const float x0 = lo16(xv), x1 = hi16(xv);
#pragma unroll
      for (int h = 0; h < 8; ++h) {
        const float a = __shfl(u, e * 8 + h);
        acc[h][0] = fmaf(a, x0, acc[h][0]);
        acc[h][1] = fmaf(a, x1, acc[h][1]);
      }
    }
  }
  // reduce den over slot bits (preserves l&7); lane h then holds head-h den
  den += __shfl_xor(den, 8);
  den += __shfl_xor(den, 16);
  den += __shfl_xor(den, 32);

  uint32_t* aggp = (uint32_t*)agg + (size_t)d * 512 + l;
#pragma unroll
  for (int h = 0; h < 8; ++h) {
    const float inv = 1.f / __shfl(den, h);
    uint32_t st = (uint32_t)f2bf(acc[h][0] * inv) |
                  ((uint32_t)f2bf(acc[h][1] * inv) << 16);
    aggp[h * 64] = st;
  }
}

// ---------------------------------------------------------------------------
// Layer-1 epilogue GEMM per head: out1[n, h*64+c] =
//   elu( agg[n,h,:] @ W1T[h*64+c,:] + b1[h*64+c] ).  grid=(8, M/64).
// ---------------------------------------------------------------------------
__global__ __launch_bounds__(256) void epi1_kernel(
    const ushort* __restrict__ agg, const ushort* __restrict__ W1T,
    const float* __restrict__ b1, ushort* __restrict__ out1, int M) {
  const int h = blockIdx.x;
  const int wave = threadIdx.x >> 6;
  const int lane = threadIdx.x & 63;
  const int rt = blockIdx.y * 4 + wave;
  const int r0 = rt * 16;
  if (r0 >= M) return;
  const int l15 = lane & 15, q = lane >> 4;
  const ushort* Ap = agg + (size_t)(r0 + l15) * 1024 + h * 128 + q * 8;
  f32x4 acc[4] = {};
#pragma unroll
  for (int k0 = 0; k0 < 128; k0 += 32) {
    bf16x8 a = *(const bf16x8*)(Ap + k0);
#pragma unroll
    for (int j = 0; j < 4; ++j) {
      const bf16x8 b = *(const bf16x8*)(W1T + (size_t)(h * 64 + j * 16 + l15) *
                                                  128 + q * 8 + k0);
      acc[j] = __builtin_amdgcn_mfma_f32_16x16x32_bf16(a, b, acc[j], 0, 0, 0);
    }
  }
#pragma unroll
  for (int j = 0; j < 4; ++j) {
    const int c = h * 64 + j * 16 + l15;
    const float bb = b1[c];
#pragma unroll
    for (int r = 0; r < 4; ++r) {
      float v = acc[j][r] + bb;
      v = (v > 0.f) ? v : __expf(v) - 1.f;
      out1[(size_t)(r0 + q * 4 + r) * 512 + c] = f2bf(v);
    }
  }
}

// ---------------------------------------------------------------------------
// Attention layers 2/3: H=1, C=64, h bf16. One wave per node (round-6 best).
// ---------------------------------------------------------------------------
__global__ __launch_bounds__(256) void attn_h1_kernel(
    const int* __restrict__ indptr, const int* __restrict__ csr_src,
    const float* __restrict__ al_s, const float* __restrict__ al_d,
    const ushort* __restrict__ hin, const float* __restrict__ bias,
    ushort* __restrict__ outp, int Nn) {
  int w = (blockIdx.x * 256 + threadIdx.x) >> 6;
  int lane = threadIdx.x & 63;
  if (w >= Nn) return;
  const int d = w;
  const int start = indptr[d];
  const int deg = indptr[d + 1] - start;
  const int total = deg + 1;
  const float ald = al_d[d];

  float acc = 0.f, den = 0.f;
  for (int e0 = 0; e0 < total; e0 += 64) {
    int e = e0 + lane;
    int s_j = d;
    float u = 0.f;
    if (e < total) {
      s_j = (e < deg) ? csr_src[start + e] : d;
      float v = al_s[s_j] + ald;
      v = fmaxf(v, NEG_SLOPE * v);
      u = __expf(v);
      den += u;
    }
    int ne = min(64, total - e0);
    for (int j = 0; j < ne; j += 8) {
      float av[8];
      int sv[8];
#pragma unroll
      for (int k = 0; k < 8; ++k) {
        av[k] = __shfl(u, j + k);
        sv[k] = __shfl(s_j, j + k);
      }
      float hv[8];
#pragma unroll
      for (int k = 0; k < 8; ++k)
        hv[k] = bf2f(hin[(size_t)sv[k] * 64 + lane]);
#pragma unroll
      for (int k = 0; k < 8; ++k) acc = fmaf(av[k], hv[k], acc);
    }
  }
#pragma unroll
  for (int off = 32; off; off >>= 1) den += __shfl_xor(den, off);
  float v = acc / den + bias[lane];
  v = (v > 0.f) ? v : __expf(v) - 1.f;
  outp[(size_t)d * 64 + lane] = f2bf(v);
}

// ---------------------------------------------------------------------------
// Attention layer 3 + pooling: atomicAdd into per-graph sums.
// ---------------------------------------------------------------------------
__global__ __launch_bounds__(256) void attn_h1_pool_kernel(
    const int* __restrict__ indptr, const int* __restrict__ csr_src,
    const float* __restrict__ al_s, const float* __restrict__ al_d,
    const ushort* __restrict__ hin, const float* __restrict__ bias,
    const int* __restrict__ batch, float* __restrict__ sums, int Nn) {
  int w = (blockIdx.x * 256 + threadIdx.x) >> 6;
  int lane = threadIdx.x & 63;
  if (w >= Nn) return;
  const int d = w;
  const int start = indptr[d];
  const int deg = indptr[d + 1] - start;
  const int total = deg + 1;
  const float ald = al_d[d];

  float acc = 0.f, den = 0.f;
  for (int e0 = 0; e0 < total; e0 += 64) {
    int e = e0 + lane;
    int s_j = d;
    float u = 0.f;
    if (e < total) {
      s_j = (e < deg) ? csr_src[start + e] : d;
      float v = al_s[s_j] + ald;
      v = fmaxf(v, NEG_SLOPE * v);
      u = __expf(v);
      den += u;
    }
    int ne = min(64, total - e0);
    for (int j = 0; j < ne; j += 8) {
      float av[8];
      int sv[8];
#pragma unroll
      for (int k = 0; k < 8; ++k) {
        av[k] = __shfl(u, j + k);
        sv[k] = __shfl(s_j, j + k);
      }
      float hv[8];
#pragma unroll
      for (int k = 0; k < 8; ++k)
        hv[k] = bf2f(hin[(size_t)sv[k] * 64 + lane]);
#pragma unroll
      for (int k = 0; k < 8; ++k) acc = fmaf(av[k], hv[k], acc);
    }
  }
#pragma unroll
  for (int off = 32; off; off >>= 1) den += __shfl_xor(den, off);
  float v = acc / den + bias[lane];
  v = (v > 0.f) ? v : __expf(v) - 1.f;
  atomicAdd(&sums[batch[d] * 64 + lane], v);
}

// ---------------------------------------------------------------------------
// Final FC on pooled sums. One block.
// ---------------------------------------------------------------------------
__global__ __launch_bounds__(256) void fc_kernel(
    const float* __restrict__ sums, const int* __restrict__ batch, int Nn,
    const float* __restrict__ fcW, const float* __restrict__ fcb,
    float* __restrict__ out) {
  __shared__ int lb[65];
  __shared__ float inv_cnt[64];
  int tid = threadIdx.x;
  if (tid <= 64) {
    int lo = 0, hi = Nn;
    while (lo < hi) {
      int mid = (lo + hi) >> 1;
      if (batch[mid] < tid) lo = mid + 1; else hi = mid;
    }
    lb[tid] = lo;
  }
  __syncthreads();
  if (tid < 64) inv_cnt[tid] = 1.f / fmaxf((float)(lb[tid + 1] - lb[tid]), 1.f);
  __syncthreads();
  for (int i = tid; i < 64 * 10; i += 256) {
    int g = i / 10, o = i % 10;
    float acc = fcb[o];
    float inv = inv_cnt[g];
    for (int c = 0; c < 64; ++c)
      acc = fmaf(sums[g * 64 + c] * inv, fcW[c * 10 + o], acc);
    out[i] = acc;
  }
}

// ---------------------------------------------------------------------------
extern "C" void kernel_launch(void* const* d_in, const int* in_sizes, int n_in,
                              void* d_out, int out_size, void* d_ws,
                              size_t ws_size, hipStream_t stream) {
  const float* x = (const float*)d_in[0];
  const int* ei = (const int*)d_in[1];
  const int* batch = (const int*)d_in[2];
  const float* W1 = (const float*)d_in[3];
  const float* a1s = (const float*)d_in[4];
  const float* a1d = (const float*)d_in[5];
  const float* b1 = (const float*)d_in[6];
  const float* W2 = (const float*)d_in[7];
  const float* a2s = (const float*)d_in[8];
  const float* a2d = (const float*)d_in[9];
  const float* b2 = (const float*)d_in[10];
  const float* W3 = (const float*)d_in[11];
  const float* a3s = (const float*)d_in[12];
  const float* a3d = (const float*)d_in[13];
  const float* b3 = (const float*)d_in[14];
  const float* fcW = (const float*)d_in[15];
  const float* fcb = (const float*)d_in[16];
  float* out = (float*)d_out;

  const int N = in_sizes[0] / 128;  // 50000
  const int E = in_sizes[1] / 2;    // 800000
  const int* srcp = ei;
  const int* dstp = ei + E;

  // --- workspace layout ---
  char* ws = (char*)d_ws;
  size_t off = 0;
  auto alloc = [&](size_t bytes) -> void* {
    off = (off + 255) & ~(size_t)255;
    void* p = ws + off;
    off += bytes;
    return p;
  };
  ushort* x_bf = (ushort*)alloc((size_t)N * 128 * 2);
  ushort* W1T = (ushort*)alloc(512 * 128 * 2);
  ushort* W2T = (ushort*)alloc(64 * 512 * 2);
  ushort* W3T = (ushort*)alloc(64 * 64 * 2);
  ushort* agg = (ushort*)alloc((size_t)N * 1024 * 2);  // [N][8][128] bf16
  ushort* out1 = (ushort*)alloc((size_t)N * 512 * 2);
  float* al_s1 = (float*)alloc((size_t)N * 8 * 4);
  float* al_d1 = (float*)alloc((size_t)N * 8 * 4);
  float* al_s2 = (float*)alloc((size_t)N * 4);
  float* al_d2 = (float*)alloc((size_t)N * 4);
  float* al_s3 = (float*)alloc((size_t)N * 4);
  float* al_d3 = (float*)alloc((size_t)N * 4);
  int* cnt = (int*)alloc((size_t)N * 4);
  int* fill = (int*)alloc((size_t)(N + 1) * 4);
  int* indptr = (int*)alloc((size_t)(N + 1) * 4);
  int* csr = (int*)alloc((size_t)E * 4);
  int* incbuf = (int*)alloc((size_t)N * 4);
  int* bsum = (int*)alloc(1024 * 4);
  float* sums = (float*)alloc(64 * 64 * 4);

  // aliases into the (dead-after-epi1) agg region
  ushort* h2 = agg;
  ushort* out2 = agg + (size_t)N * 64;
  ushort* h3 = agg + (size_t)2 * N * 64;

  hipMemsetAsync(cnt, 0, (size_t)N * 4, stream);

  const int scan_blocks = (N + 255) / 256;  // 196 (<256 required)
  const int row_blocks = (N / 16 + 3) / 4;  // 782

  // prep: x cast + weight transposes + CSR count + sums zero
  const int n_x4 = N * 128 / 4;
  const int prep_total = n_x4 + 512 * 128 + 64 * 512 + 64 * 64 + E + 64 * 64;
  prep_kernel<<<(prep_total + 255) / 256, 256, 0, stream>>>(
      (const float4*)x, (uint2*)x_bf, n_x4, W1, W1T, W2, W2T, W3, W3T, dstp,
      cnt, sums, E);

  // GEMM1 logits (al only, no h1 store), fused with block-scan of cnt
  const int gemmBlocks = 4 * row_blocks;
  gemm1_scan_kernel<<<gemmBlocks + scan_blocks, 256, 0, stream>>>(
      x_bf, W1T, a1s, a1d, al_s1, al_d1, N, gemmBlocks, cnt, incbuf, bsum, N);
  scan_final2<<<scan_blocks, 256, 0, stream>>>(incbuf, bsum, indptr, fill, N);
  scatter_kernel<<<(E + 255) / 256, 256, 0, stream>>>(srcp, dstp, fill, csr, E);

  // Layer 1: aggregate x in alpha-space, then per-head epilogue GEMM
  attn1_agg_kernel<<<(N + 3) / 4, 256, 0, stream>>>(
      indptr, csr, al_s1, al_d1, (const uint32_t*)x_bf, agg, N);
  epi1_kernel<<<dim3(8, row_blocks), 256, 0, stream>>>(agg, W1T, b1, out1, N);

  // Layer 2
  gemm_n64_al<<<dim3(1, row_blocks), 256, 0, stream>>>(out1, W2T, h2, a2s, a2d,
                                                       al_s2, al_d2, N, 512);
  attn_h1_kernel<<<(N + 3) / 4, 256, 0, stream>>>(indptr, csr, al_s2, al_d2, h2,
                                                  b2, out2, N);

  // Layer 3 (+ fused pooling)
  gemm_n64_al<<<dim3(1, row_blocks), 256, 0, stream>>>(out2, W3T, h3, a3s, a3d,
                                                       al_s3, al_d3, N, 64);
  attn_h1_pool_kernel<<<(N + 3) / 4, 256, 0, stream>>>(
      indptr, csr, al_s3, al_d3, h3, b3, batch, sums, N);

  // Final FC
  fc_kernel<<<1, 256, 0, stream>>>(sums, batch, N, fcW, fcb, out);
}

// Round 11
// 579.130 us; speedup vs baseline: 1.0029x; 1.0029x over previous
//
#include <hip/hip_runtime.h>
#include <hip/hip_bf16.h>
#include <cstdint>

#define NEG_SLOPE 0.2f

typedef __attribute__((ext_vector_type(8))) short bf16x8;
typedef __attribute__((ext_vector_type(4))) float f32x4;

__device__ __forceinline__ float bf2f(uint32_t u) {
  union { float f; uint32_t i; } v;
  v.i = u << 16;
  return v.f;
}
__device__ __forceinline__ float lo16(uint32_t u) {
  union { float f; uint32_t i; } v;
  v.i = u << 16;
  return v.f;
}
__device__ __forceinline__ float hi16(uint32_t u) {
  union { float f; uint32_t i; } v;
  v.i = u & 0xffff0000u;
  return v.f;
}
__device__ __forceinline__ ushort f2bf(float f) {
  union { float f; uint32_t i; } v;
  v.f = f;
  uint32_t r = v.i + 0x7FFF + ((v.i >> 16) & 1);  // round-nearest-even
  return (ushort)(r >> 16);
}

// ---------------------------------------------------------------------------
// prep: cast x -> bf16, transpose+cast W1/W2/W3, CSR count pass, zero sums.
// ---------------------------------------------------------------------------
__global__ void prep_kernel(const float4* __restrict__ x,
                            uint2* __restrict__ x_bf, int n_x4,
                            const float* __restrict__ W1,
                            ushort* __restrict__ W1T,
                            const float* __restrict__ W2,
                            ushort* __restrict__ W2T,
                            const float* __restrict__ W3,
                            ushort* __restrict__ W3T,
                            const int* __restrict__ dst, int* __restrict__ cnt,
                            float* __restrict__ sums, int E) {
  int i = blockIdx.x * 256 + threadIdx.x;
  const int r0 = n_x4;
  const int r1 = r0 + 512 * 128;
  const int r2 = r1 + 64 * 512;
  const int r3 = r2 + 64 * 64;
  const int r4 = r3 + E;
  const int r5 = r4 + 64 * 64;
  if (i < r0) {
    float4 v = x[i];
    uint2 o;
    o.x = (uint32_t)f2bf(v.x) | ((uint32_t)f2bf(v.y) << 16);
    o.y = (uint32_t)f2bf(v.z) | ((uint32_t)f2bf(v.w) << 16);
    x_bf[i] = o;
  } else if (i < r1) {
    int idx = i - r0;
    int n = idx >> 7, k = idx & 127;
    W1T[idx] = f2bf(W1[(size_t)k * 512 + n]);
  } else if (i < r2) {
    int idx = i - r1;
    int n = idx >> 9, k = idx & 511;
    W2T[idx] = f2bf(W2[(size_t)k * 64 + n]);
  } else if (i < r3) {
    int idx = i - r2;
    int n = idx >> 6, k = idx & 63;
    W3T[idx] = f2bf(W3[(size_t)k * 64 + n]);
  } else if (i < r4) {
    atomicAdd(&cnt[dst[i - r3]], 1);
  } else if (i < r5) {
    sums[i - r4] = 0.f;
  }
}

// ---------------------------------------------------------------------------
// Fused dispatch: GEMM1(+al, C stored) for blocks [0, gemmBlocks);
// block-scan tail blocks.
// ---------------------------------------------------------------------------
__global__ __launch_bounds__(256) void gemm1_scan_kernel(
    const ushort* __restrict__ A, const ushort* __restrict__ BT,
    ushort* __restrict__ C, const float* __restrict__ a1s,
    const float* __restrict__ a1d, float* __restrict__ al_s,
    float* __restrict__ al_d, int M, int gemmBlocks,
    const int* __restrict__ scan_in, int* __restrict__ scan_out,
    int* __restrict__ bsum, int n) {
  if (blockIdx.x >= gemmBlocks) {
    __shared__ int sm[256];
    const int sb = blockIdx.x - gemmBlocks;
    int gid = sb * 256 + threadIdx.x;
    int v = (gid < n) ? scan_in[gid] : 0;
    sm[threadIdx.x] = v;
    __syncthreads();
    for (int off = 1; off < 256; off <<= 1) {
      int t = (threadIdx.x >= off) ? sm[threadIdx.x - off] : 0;
      __syncthreads();
      sm[threadIdx.x] += t;
      __syncthreads();
    }
    if (gid < n) scan_out[gid] = sm[threadIdx.x];
    if (threadIdx.x == 255) bsum[sb] = sm[255];
    return;
  }
  const int K = 128;
  const int wave = threadIdx.x >> 6;
  const int lane = threadIdx.x & 63;
  const int bx = blockIdx.x & 3;
  const int by = blockIdx.x >> 2;
  const int rt = by * 4 + wave;
  const int r0 = rt * 16;
  if (r0 >= M) return;
  const int n0 = bx * 128;
  const int l15 = lane & 15, q = lane >> 4;
  const ushort* Ap = A + (size_t)(r0 + l15) * K + q * 8;
  f32x4 acc[8] = {};
  for (int k0 = 0; k0 < K; k0 += 32) {
    bf16x8 a = *(const bf16x8*)(Ap + k0);
#pragma unroll
    for (int j = 0; j < 8; ++j) {
      const bf16x8 b =
          *(const bf16x8*)(BT + (size_t)(n0 + j * 16 + l15) * K + q * 8 + k0);
      acc[j] = __builtin_amdgcn_mfma_f32_16x16x32_bf16(a, b, acc[j], 0, 0, 0);
    }
  }
#pragma unroll
  for (int j = 0; j < 8; ++j)
#pragma unroll
    for (int r = 0; r < 4; ++r) {
      int row = r0 + q * 4 + r;
      C[(size_t)row * 512 + n0 + j * 16 + l15] = f2bf(acc[j][r]);
    }
  float als_p[2][4] = {{0.f}};
  float ald_p[2][4] = {{0.f}};
#pragma unroll
  for (int j = 0; j < 8; ++j) {
    int head = bx * 2 + (j >> 2);
    int cih = (j & 3) * 16 + l15;
    float wsc = a1s[head * 64 + cih];
    float wdc = a1d[head * 64 + cih];
#pragma unroll
    for (int r = 0; r < 4; ++r) {
      als_p[j >> 2][r] = fmaf(acc[j][r], wsc, als_p[j >> 2][r]);
      ald_p[j >> 2][r] = fmaf(acc[j][r], wdc, ald_p[j >> 2][r]);
    }
  }
#pragma unroll
  for (int g = 0; g < 2; ++g)
#pragma unroll
    for (int r = 0; r < 4; ++r) {
      float vs = als_p[g][r], vd = ald_p[g][r];
#pragma unroll
      for (int off = 1; off < 16; off <<= 1) {
        vs += __shfl_xor(vs, off);
        vd += __shfl_xor(vd, off);
      }
      if (l15 == 0) {
        int row = r0 + q * 4 + r;
        al_s[(size_t)row * 8 + bx * 2 + g] = vs;
        al_d[(size_t)row * 8 + bx * 2 + g] = vd;
      }
    }
}

// ---------------------------------------------------------------------------
// GEMM (N=64) + fused al (H=1): C[M,64] = A[M,K] @ BT[64,K].
// ---------------------------------------------------------------------------
__global__ __launch_bounds__(256) void gemm_n64_al(
    const ushort* __restrict__ A, const ushort* __restrict__ BT,
    ushort* __restrict__ C, const float* __restrict__ asrc,
    const float* __restrict__ adst, float* __restrict__ al_s,
    float* __restrict__ al_d, int M, int K) {
  const int wave = threadIdx.x >> 6;
  const int lane = threadIdx.x & 63;
  const int rt = blockIdx.y * 4 + wave;
  const int r0 = rt * 16;
  if (r0 >= M) return;
  const int l15 = lane & 15, q = lane >> 4;
  const ushort* Ap = A + (size_t)(r0 + l15) * K + q * 8;
  f32x4 acc[4] = {};
  for (int k0 = 0; k0 < K; k0 += 32) {
    bf16x8 a = *(const bf16x8*)(Ap + k0);
#pragma unroll
    for (int j = 0; j < 4; ++j) {
      const bf16x8 b =
          *(const bf16x8*)(BT + (size_t)(j * 16 + l15) * K + q * 8 + k0);
      acc[j] = __builtin_amdgcn_mfma_f32_16x16x32_bf16(a, b, acc[j], 0, 0, 0);
    }
  }
#pragma unroll
  for (int j = 0; j < 4; ++j)
#pragma unroll
    for (int r = 0; r < 4; ++r) {
      int row = r0 + q * 4 + r;
      C[(size_t)row * 64 + j * 16 + l15] = f2bf(acc[j][r]);
    }
  float als_p[4] = {0.f, 0.f, 0.f, 0.f};
  float ald_p[4] = {0.f, 0.f, 0.f, 0.f};
#pragma unroll
  for (int j = 0; j < 4; ++j) {
    float wsc = asrc[j * 16 + l15];
    float wdc = adst[j * 16 + l15];
#pragma unroll
    for (int r = 0; r < 4; ++r) {
      als_p[r] = fmaf(acc[j][r], wsc, als_p[r]);
      ald_p[r] = fmaf(acc[j][r], wdc, ald_p[r]);
    }
  }
#pragma unroll
  for (int r = 0; r < 4; ++r) {
    float vs = als_p[r], vd = ald_p[r];
#pragma unroll
    for (int off = 1; off < 16; off <<= 1) {
      vs += __shfl_xor(vs, off);
      vd += __shfl_xor(vd, off);
    }
    if (l15 == 0) {
      int row = r0 + q * 4 + r;
      al_s[row] = vs;
      al_d[row] = vd;
    }
  }
}

__global__ void scan_final2(const int* __restrict__ inc,
                            const int* __restrict__ bsum,
                            int* __restrict__ indptr, int* __restrict__ fill,
                            int n) {
  __shared__ int sm[256];
  const int t = threadIdx.x, bx = blockIdx.x;
  sm[t] = (t < bx) ? bsum[t] : 0;  // gridDim <= 256
  __syncthreads();
  for (int off = 128; off; off >>= 1) {
    if (t < off) sm[t] += sm[t + off];
    __syncthreads();
  }
  const int prefix = sm[0];
  int gid = bx * 256 + t;
  if (gid < n) {
    int val = inc[gid] + prefix;
    indptr[gid + 1] = val;
    fill[gid + 1] = val;
  }
  if (gid == 0) {
    indptr[0] = 0;
    fill[0] = 0;
  }
}

__global__ void scatter_kernel(const int* __restrict__ src,
                               const int* __restrict__ dst,
                               int* __restrict__ fill,
                               int* __restrict__ csr_src, int E) {
  int e = blockIdx.x * 256 + threadIdx.x;
  if (e < E) {
    int pos = atomicAdd(&fill[dst[e]], 1);
    csr_src[pos] = src[e];
  }
}

// ---------------------------------------------------------------------------
// Attention layer 1: H=8, C=64, h1 bf16. ONE WAVE per dst node, no LDS.
// (Round-6 version: at the L2 compulsory-miss wall, ~131 us.)
// ---------------------------------------------------------------------------
__global__ __launch_bounds__(256) void attn1_kernel(
    const int* __restrict__ indptr, const int* __restrict__ csr_src,
    const float* __restrict__ al_s, const float* __restrict__ al_d,
    const ushort* __restrict__ h1, const float* __restrict__ b1,
    ushort* __restrict__ out1, int Nn) {
  const int w = (blockIdx.x * 256 + threadIdx.x) >> 6;
  const int l = threadIdx.x & 63;
  if (w >= Nn) return;
  const int d = w;
  const int start = indptr[d];
  const int deg = indptr[d + 1] - start;
  const int total = deg + 1;  // + self loop
  const int head = l >> 3;    // accumulation head / edge slot for this lane
  const int hh = l & 7;       // compute-stage head for this lane
  const float ald_c = al_d[(size_t)d * 8 + hh];

  float acc[8] = {0.f, 0.f, 0.f, 0.f, 0.f, 0.f, 0.f, 0.f};
  float den = 0.f;
  const ushort* h1l = h1 + l * 8;

  // prologue: prefetch group 0
  int s_p = d;
  float a_p = 0.f;
  if (head < total) {
    s_p = (head < deg) ? csr_src[start + head] : d;
    a_p = al_s[(size_t)s_p * 8 + hh];
  }

  for (int e0 = 0; e0 < total; e0 += 8) {
    const int el = e0 + head;
    const int s_j = s_p;
    float v = a_p + ald_c;
    v = fmaxf(v, NEG_SLOPE * v);
    const float u = (el < total) ? __expf(v) : 0.f;
    den += u;
    const int eln = el + 8;
    if (eln < total) {
      s_p = (eln < deg) ? csr_src[start + eln] : d;
      a_p = al_s[(size_t)s_p * 8 + hh];
    } else {
      s_p = d;
      a_p = 0.f;
    }
#pragma unroll
    for (int e = 0; e < 8; ++e) {
      const float a = __shfl(u, e * 8 + head);
      const int s = __shfl(s_j, e * 8);
      const uint4 uu = *(const uint4*)(h1l + (size_t)s * 512);
      acc[0] = fmaf(a, lo16(uu.x), acc[0]);
      acc[1] = fmaf(a, hi16(uu.x), acc[1]);
      acc[2] = fmaf(a, lo16(uu.y), acc[2]);
      acc[3] = fmaf(a, hi16(uu.y), acc[3]);
      acc[4] = fmaf(a, lo16(uu.z), acc[4]);
      acc[5] = fmaf(a, hi16(uu.z), acc[5]);
      acc[6] = fmaf(a, lo16(uu.w), acc[6]);
      acc[7] = fmaf(a, hi16(uu.w), acc[7]);
    }
  }
  den += __shfl_xor(den, 8);
  den += __shfl_xor(den, 16);
  den += __shfl_xor(den, 32);
  const float inv = 1.f / __shfl(den, head);

  const float4 bb0 = *(const float4*)(b1 + l * 8);
  const float4 bb1 = *(const float4*)(b1 + l * 8 + 4);
  float o[8];
  o[0] = acc[0] * inv + bb0.x;
  o[1] = acc[1] * inv + bb0.y;
  o[2] = acc[2] * inv + bb0.z;
  o[3] = acc[3] * inv + bb0.w;
  o[4] = acc[4] * inv + bb1.x;
  o[5] = acc[5] * inv + bb1.y;
  o[6] = acc[6] * inv + bb1.z;
  o[7] = acc[7] * inv + bb1.w;
#pragma unroll
  for (int k = 0; k < 8; ++k) o[k] = (o[k] > 0.f) ? o[k] : __expf(o[k]) - 1.f;
  uint4 st;
  st.x = (uint32_t)f2bf(o[0]) | ((uint32_t)f2bf(o[1]) << 16);
  st.y = (uint32_t)f2bf(o[2]) | ((uint32_t)f2bf(o[3]) << 16);
  st.z = (uint32_t)f2bf(o[4]) | ((uint32_t)f2bf(o[5]) << 16);
  st.w = (uint32_t)f2bf(o[6]) | ((uint32_t)f2bf(o[7]) << 16);
  *(uint4*)(out1 + (size_t)d * 512 + l * 8) = st;
}

// ---------------------------------------------------------------------------
// Attention layers 2/3 (H=1, C=64): one wave per node, PAIR-LOAD scheme.
// Lanes 0-31 cover the full 128B row of even edges (2 ch/lane via dword),
// lanes 32-63 cover odd edges. Halves VMEM instr + shuffles per edge vs
// round-6; fma count unchanged; one shfl_xor(32) combine at the end.
// DO_POOL: atomicAdd into per-graph sums instead of storing.
// ---------------------------------------------------------------------------
template <int DO_POOL>
__global__ __launch_bounds__(256) void attn_h1_pair(
    const int* __restrict__ indptr, const int* __restrict__ csr_src,
    const float* __restrict__ al_s, const float* __restrict__ al_d,
    const ushort* __restrict__ hin, const float* __restrict__ bias,
    ushort* __restrict__ outp, const int* __restrict__ batch,
    float* __restrict__ sums, int Nn) {
  int w = (blockIdx.x * 256 + threadIdx.x) >> 6;
  int lane = threadIdx.x & 63;
  if (w >= Nn) return;
  const int d = w;
  const int start = indptr[d];
  const int deg = indptr[d + 1] - start;
  const int total = deg + 1;
  const float ald = al_d[d];
  const int li = lane & 31;    // channel pair index: channels 2li, 2li+1
  const int par = lane >> 5;   // edge parity this lane accumulates

  float acc0 = 0.f, acc1 = 0.f, den = 0.f;
  const ushort* hl = hin + 2 * li;

  for (int e0 = 0; e0 < total; e0 += 64) {
    int e = e0 + lane;
    int s_j = d;
    float u = 0.f;
    if (e < total) {
      s_j = (e < deg) ? csr_src[start + e] : d;
      float v = al_s[s_j] + ald;
      v = fmaxf(v, NEG_SLOPE * v);
      u = __expf(v);
      den += u;
    }
    int ne = min(64, total - e0);
    for (int j = 0; j < ne; j += 16) {
      float av[8];
      int sv[8];
#pragma unroll
      for (int k = 0; k < 8; ++k) {
        const int idx = j + 2 * k + par;  // this lane's edge of pair k
        av[k] = __shfl(u, idx);
        sv[k] = __shfl(s_j, idx);
      }
      uint32_t hv[8];
#pragma unroll
      for (int k = 0; k < 8; ++k)
        hv[k] = *(const uint32_t*)(hl + (size_t)sv[k] * 64);
#pragma unroll
      for (int k = 0; k < 8; ++k) {
        acc0 = fmaf(av[k], lo16(hv[k]), acc0);
        acc1 = fmaf(av[k], hi16(hv[k]), acc1);
      }
    }
  }
#pragma unroll
  for (int off = 32; off; off >>= 1) den += __shfl_xor(den, off);
  // combine even/odd edge partials across the two half-waves
  acc0 += __shfl_xor(acc0, 32);
  acc1 += __shfl_xor(acc1, 32);
  if (lane < 32) {
    const float inv = 1.f / den;
    float v0 = acc0 * inv + bias[2 * li];
    float v1 = acc1 * inv + bias[2 * li + 1];
    v0 = (v0 > 0.f) ? v0 : __expf(v0) - 1.f;
    v1 = (v1 > 0.f) ? v1 : __expf(v1) - 1.f;
    if (DO_POOL) {
      float* sp = sums + batch[d] * 64 + 2 * li;
      atomicAdd(sp, v0);
      atomicAdd(sp + 1, v1);
    } else {
      *(uint32_t*)(outp + (size_t)d * 64 + 2 * li) =
          (uint32_t)f2bf(v0) | ((uint32_t)f2bf(v1) << 16);
    }
  }
}

// ---------------------------------------------------------------------------
// Final FC on pooled sums. One block.
// ---------------------------------------------------------------------------
__global__ __launch_bounds__(256) void fc_kernel(
    const float* __restrict__ sums, const int* __restrict__ batch, int Nn,
    const float* __restrict__ fcW, const float* __restrict__ fcb,
    float* __restrict__ out) {
  __shared__ int lb[65];
  __shared__ float inv_cnt[64];
  int tid = threadIdx.x;
  if (tid <= 64) {
    int lo = 0, hi = Nn;
    while (lo < hi) {
      int mid = (lo + hi) >> 1;
      if (batch[mid] < tid) lo = mid + 1; else hi = mid;
    }
    lb[tid] = lo;
  }
  __syncthreads();
  if (tid < 64) inv_cnt[tid] = 1.f / fmaxf((float)(lb[tid + 1] - lb[tid]), 1.f);
  __syncthreads();
  for (int i = tid; i < 64 * 10; i += 256) {
    int g = i / 10, o = i % 10;
    float acc = fcb[o];
    float inv = inv_cnt[g];
    for (int c = 0; c < 64; ++c)
      acc = fmaf(sums[g * 64 + c] * inv, fcW[c * 10 + o], acc);
    out[i] = acc;
  }
}

// ---------------------------------------------------------------------------
extern "C" void kernel_launch(void* const* d_in, const int* in_sizes, int n_in,
                              void* d_out, int out_size, void* d_ws,
                              size_t ws_size, hipStream_t stream) {
  const float* x = (const float*)d_in[0];
  const int* ei = (const int*)d_in[1];
  const int* batch = (const int*)d_in[2];
  const float* W1 = (const float*)d_in[3];
  const float* a1s = (const float*)d_in[4];
  const float* a1d = (const float*)d_in[5];
  const float* b1 = (const float*)d_in[6];
  const float* W2 = (const float*)d_in[7];
  const float* a2s = (const float*)d_in[8];
  const float* a2d = (const float*)d_in[9];
  const float* b2 = (const float*)d_in[10];
  const float* W3 = (const float*)d_in[11];
  const float* a3s = (const float*)d_in[12];
  const float* a3d = (const float*)d_in[13];
  const float* b3 = (const float*)d_in[14];
  const float* fcW = (const float*)d_in[15];
  const float* fcb = (const float*)d_in[16];
  float* out = (float*)d_out;

  const int N = in_sizes[0] / 128;  // 50000
  const int E = in_sizes[1] / 2;    // 800000
  const int* srcp = ei;
  const int* dstp = ei + E;

  // --- workspace layout ---
  char* ws = (char*)d_ws;
  size_t off = 0;
  auto alloc = [&](size_t bytes) -> void* {
    off = (off + 255) & ~(size_t)255;
    void* p = ws + off;
    off += bytes;
    return p;
  };
  ushort* x_bf = (ushort*)alloc((size_t)N * 128 * 2);
  ushort* W1T = (ushort*)alloc(512 * 128 * 2);
  ushort* W2T = (ushort*)alloc(64 * 512 * 2);
  ushort* W3T = (ushort*)alloc(64 * 64 * 2);
  ushort* h1 = (ushort*)alloc((size_t)N * 512 * 2);  // reused: h2/out2/h3
  ushort* out1 = (ushort*)alloc((size_t)N * 512 * 2);
  float* al_s1 = (float*)alloc((size_t)N * 8 * 4);
  float* al_d1 = (float*)alloc((size_t)N * 8 * 4);
  float* al_s2 = (float*)alloc((size_t)N * 4);
  float* al_d2 = (float*)alloc((size_t)N * 4);
  float* al_s3 = (float*)alloc((size_t)N * 4);
  float* al_d3 = (float*)alloc((size_t)N * 4);
  int* cnt = (int*)alloc((size_t)N * 4);
  int* fill = (int*)alloc((size_t)(N + 1) * 4);
  int* indptr = (int*)alloc((size_t)(N + 1) * 4);
  int* csr = (int*)alloc((size_t)E * 4);
  int* incbuf = (int*)alloc((size_t)N * 4);
  int* bsum = (int*)alloc(1024 * 4);
  float* sums = (float*)alloc(64 * 64 * 4);

  // aliases into the (dead-after-attn1) h1 region
  ushort* h2 = h1;
  ushort* out2 = h1 + (size_t)N * 64;
  ushort* h3 = h1 + (size_t)2 * N * 64;

  hipMemsetAsync(cnt, 0, (size_t)N * 4, stream);

  const int scan_blocks = (N + 255) / 256;  // 196 (<256 required)
  const int row_blocks = (N / 16 + 3) / 4;  // 782

  // prep: x cast + weight transposes + CSR count + sums zero
  const int n_x4 = N * 128 / 4;
  const int prep_total = n_x4 + 512 * 128 + 64 * 512 + 64 * 64 + E + 64 * 64;
  prep_kernel<<<(prep_total + 255) / 256, 256, 0, stream>>>(
      (const float4*)x, (uint2*)x_bf, n_x4, W1, W1T, W2, W2T, W3, W3T, dstp,
      cnt, sums, E);

  // GEMM1 + al1 (C stored), fused with block-scan of cnt
  const int gemmBlocks = 4 * row_blocks;
  gemm1_scan_kernel<<<gemmBlocks + scan_blocks, 256, 0, stream>>>(
      x_bf, W1T, h1, a1s, a1d, al_s1, al_d1, N, gemmBlocks, cnt, incbuf, bsum,
      N);
  scan_final2<<<scan_blocks, 256, 0, stream>>>(incbuf, bsum, indptr, fill, N);
  scatter_kernel<<<(E + 255) / 256, 256, 0, stream>>>(srcp, dstp, fill, csr, E);

  // Layer 1 attention + bias + ELU (wave per node)
  attn1_kernel<<<(N + 3) / 4, 256, 0, stream>>>(indptr, csr, al_s1, al_d1, h1,
                                                b1, out1, N);

  // Layer 2
  gemm_n64_al<<<dim3(1, row_blocks), 256, 0, stream>>>(out1, W2T, h2, a2s, a2d,
                                                       al_s2, al_d2, N, 512);
  attn_h1_pair<0><<<(N + 3) / 4, 256, 0, stream>>>(
      indptr, csr, al_s2, al_d2, h2, b2, out2, batch, sums, N);

  // Layer 3 (+ fused pooling)
  gemm_n64_al<<<dim3(1, row_blocks), 256, 0, stream>>>(out2, W3T, h3, a3s, a3d,
                                                       al_s3, al_d3, N, 64);
  attn_h1_pair<1><<<(N + 3) / 4, 256, 0, stream>>>(
      indptr, csr, al_s3, al_d3, h3, b3, nullptr, batch, sums, N);

  // Final FC
  fc_kernel<<<1, 256, 0, stream>>>(sums, batch, N, fcW, fcb, out);
}